// Round 11
// baseline (566.741 us; speedup 1.0000x reference)
//
#include <hip/hip_runtime.h>

#define D 128
#define BN_EPS 1e-5f
#define NBUCK 512     // coarse buckets, dst>>8 (391 used at N=100K), 256 nodes/bucket
#define BSHIFT 8
#define BNODES 256    // nodes per bucket
#define CAP 4608      // padded slots/bucket; mean fill 4096 (+8 sigma)

using short8 = __attribute__((ext_vector_type(8))) short;
using floatx4 = __attribute__((ext_vector_type(4))) float;

__device__ inline unsigned short f2bf(float f) {
    unsigned u = __float_as_uint(f);
    u += 0x7fff + ((u >> 16) & 1);  // RNE
    return (unsigned short)(u >> 16);
}
__device__ inline float bf2f(unsigned short s) {
    return __uint_as_float(((unsigned)s) << 16);
}

// ---------- init: zero resCnt/dcnt/dcur + perm pad + Wt + BN affine ----------
__global__ __launch_bounds__(256) void init_kernel(
    const float* __restrict__ W, const float* __restrict__ b,
    const float* __restrict__ gamma, const float* __restrict__ beta,
    const float* __restrict__ mean, const float* __restrict__ var,
    unsigned short* __restrict__ Wt, float* __restrict__ scv,
    float* __restrict__ pov, int* __restrict__ resCnt,
    int* __restrict__ dbins /*256 ints: dcnt[0..127], dcur[128..255]*/,
    int* __restrict__ perm, int N) {
    int t = blockIdx.x * 256 + threadIdx.x;  // 0..16383 == D*D
    Wt[(size_t)(t & 127) * D + (t >> 7)] = f2bf(W[t]);
    if (t < NBUCK) resCnt[t] = 0;
    if (t < 256) dbins[t] = 0;
    if (t < 16) perm[N + t] = N;  // pad tail tile slots -> guarded out
    if (t < D) {
        float sc = gamma[t] * rsqrtf(var[t] + BN_EPS);
        scv[t] = sc;
        pov[t] = (b[t] - mean[t]) * sc + beta[t];
    }
}

// ---------- pB: partition into CAPACITY-PADDED buckets (no histogram!) ----
// 128 blocks: chunk ~12500 -> per-(block,bucket) runs ~32 edges x 4B = one
// full 128B line -> no read-allocate RMW (the R7-measured scatter wall).
// pairs entry = (dst&255)<<24 | src  (valid: N < 2^24).
__global__ __launch_bounds__(512) void pB_kernel(const int* __restrict__ src,
                                                 const int* __restrict__ dst,
                                                 int* __restrict__ resCnt,
                                                 unsigned int* __restrict__ pairs,
                                                 int E) {
    __shared__ int lh[NBUCK];
    __shared__ int lcur[NBUCK];
    int tid = threadIdx.x;
    lh[tid] = 0;
    __syncthreads();
    int chunk = (E + gridDim.x - 1) / gridDim.x;
    int base = blockIdx.x * chunk;
    int lim = min(chunk, E - base);
    if (lim <= 0) return;
    for (int i = tid; i < lim; i += 512) atomicAdd(&lh[dst[base + i] >> BSHIFT], 1);
    __syncthreads();
    int c = lh[tid];
    lcur[tid] = tid * CAP + (c ? atomicAdd(&resCnt[tid], c) : 0);
    __syncthreads();
    for (int i = tid; i < lim; i += 512) {
        int s = src[base + i], d2 = dst[base + i];
        int b2 = d2 >> BSHIFT;
        int pos = atomicAdd(&lcur[b2], 1);
        if (pos < (b2 + 1) * CAP)
            pairs[pos] = (((unsigned)d2 & 255u) << 24) | (unsigned)s;
    }
}

// ---------- sortxs: per-bucket counting sort + premult xs + deg-histogram ----
__global__ __launch_bounds__(512) void sortxs_kernel(
    const unsigned int* __restrict__ pairs, const int* __restrict__ resCnt,
    const int* __restrict__ src, const int* __restrict__ dst,
    const float* __restrict__ x, int* __restrict__ deg, int* __restrict__ offs,
    int* __restrict__ colidx, float* __restrict__ dinv,
    unsigned short* __restrict__ xs, int* __restrict__ dcnt, int N, int E) {
    __shared__ int sb[NBUCK];
    __shared__ int lh[BNODES];
    __shared__ int lcur[BNODES];
    __shared__ float sdv[BNODES];
    __shared__ int ldh[128];
    int tid = threadIdx.x;
    int b = blockIdx.x;
    sb[tid] = resCnt[tid];
    if (tid < 128) ldh[tid] = 0;
    __syncthreads();
    for (int d = 1; d < NBUCK; d <<= 1) {
        int v = (tid >= d) ? sb[tid - d] : 0;
        __syncthreads();
        sb[tid] += v;
        __syncthreads();
    }
    int cnt = resCnt[b];
    int cbase = sb[b] - cnt;       // compact colidx base
    int pbase = b * CAP;           // padded pairs base
    if (tid < BNODES) lh[tid] = 0;
    __syncthreads();

    if (cnt <= CAP) {
        // ---- normal path ----
        for (int i = tid; i < cnt; i += 512)
            atomicAdd(&lh[pairs[pbase + i] >> 24], 1);
        __syncthreads();
        int orig = (tid < BNODES) ? lh[tid] : 0;
        for (int d = 1; d < BNODES; d <<= 1) {
            int v = (tid < BNODES && tid >= d) ? lh[tid - d] : 0;
            __syncthreads();
            if (tid < BNODES) lh[tid] += v;
            __syncthreads();
        }
        if (tid < BNODES) {
            int exc = lh[tid] - orig;
            int node = b * BNODES + tid;
            float dvv = rsqrtf((float)(orig + 1));
            sdv[tid] = dvv;
            if (node < N) {
                deg[node] = orig;
                offs[node] = cbase + exc;
                dinv[node] = dvv;
                atomicAdd(&ldh[min(orig, 127)], 1);
            }
            lcur[tid] = exc;
        }
        __syncthreads();
        for (int i = tid; i < cnt; i += 512) {
            unsigned int p = pairs[pbase + i];
            int pos = atomicAdd(&lcur[p >> 24], 1);
            colidx[cbase + pos] = (int)(p & 0x00FFFFFFu);
        }
    } else {
        // ---- overflow recovery: exact deg from full edge scan; no colidx ----
        for (int i = tid; i < E; i += 512) {
            int d2 = dst[i];
            if ((d2 >> BSHIFT) == b) atomicAdd(&lh[d2 & 255], 1);
        }
        __syncthreads();
        if (tid < BNODES) {
            int orig = lh[tid];
            int node = b * BNODES + tid;
            float dvv = rsqrtf((float)(orig + 1));
            sdv[tid] = dvv;
            if (node < N) {
                deg[node] = orig;
                offs[node] = -1;  // aggemm falls back to full scan for this node
                dinv[node] = dvv;
                atomicAdd(&ldh[min(orig, 127)], 1);
            }
        }
        __syncthreads();
    }
    // flush degree histogram (ldh complete before the pre-scatter barrier)
    if (tid < 128 && ldh[tid]) atomicAdd(&dcnt[tid], ldh[tid]);

    // ---- xs build for this bucket's nodes: xs = bf16(dinv[n] * x[n]) ----
    int nb = min(BNODES, N - b * BNODES);
    if (nb > 0) {
        const float4* x4 = (const float4*)x;
        ushort4* xs4 = (ushort4*)xs;
        int tot = nb * 32;  // 32 float4 chunks per node
        for (int c2 = tid; c2 < tot; c2 += 512) {
            int nl = c2 >> 5, q = c2 & 31;
            int node = b * BNODES + nl;
            float dvv = sdv[nl];
            float4 f = x4[(size_t)node * 32 + q];
            ushort4 o;
            o.x = f2bf(dvv * f.x); o.y = f2bf(dvv * f.y);
            o.z = f2bf(dvv * f.z); o.w = f2bf(dvv * f.w);
            xs4[(size_t)node * 32 + q] = o;
        }
    }
}

// ---------- dperm: degree-balanced node permutation (counting sort) ----------
// Every block redundantly LDS-scans the 128-bin dcnt (512B broadcast), then
// grid-strides nodes: pos = excl[d] + atomicAdd(dcur[d]); perm[pos] = node.
// aggemm tiles of 16 consecutive perm entries then have ~equal degree ->
// kills the R10-measured barrier tail (2.9 vs 3.69 TB/s).
__global__ __launch_bounds__(256) void dperm_kernel(
    const int* __restrict__ deg, const int* __restrict__ dcnt,
    int* __restrict__ dcur, int* __restrict__ perm, int N) {
    __shared__ int inc[128];
    __shared__ int exc[128];
    int tid = threadIdx.x;
    int orig = (tid < 128) ? dcnt[tid] : 0;
    if (tid < 128) inc[tid] = orig;
    __syncthreads();
    for (int d = 1; d < 128; d <<= 1) {
        int v = (tid < 128 && tid >= d) ? inc[tid - d] : 0;
        __syncthreads();
        if (tid < 128) inc[tid] += v;
        __syncthreads();
    }
    if (tid < 128) exc[tid] = inc[tid] - orig;
    __syncthreads();
    int gsz = gridDim.x * 256;
    for (int n = blockIdx.x * 256 + tid; n < N; n += gsz) {
        int d = min(deg[n], 127);
        int pos = exc[d] + atomicAdd(&dcur[d], 1);
        perm[pos] = n;
    }
}

// ---------- FUSED gather + MFMA GEMM + BN + ReLU + residual (perm-tiled) ----
// Block = 1024 threads = 16 waves; wave w handles node perm[row0+w] (one node
// per wave = proven 83.6us gather loop). Degree-balanced tiles -> barrier
// tail ~1. GEMM phase writes rows through perm (512B/row = 4 full lines).
__global__ __launch_bounds__(1024, 8) void aggemm_kernel(
    const unsigned short* __restrict__ xs, const float* __restrict__ dinv,
    const int* __restrict__ offs, const int* __restrict__ deg,
    const int* __restrict__ colidx, const int* __restrict__ src,
    const int* __restrict__ dst, const float* __restrict__ xg,
    const unsigned short* __restrict__ Wt, const float* __restrict__ scv,
    const float* __restrict__ pov, const int* __restrict__ perm,
    float* __restrict__ outp, int N, int E) {
    __shared__ unsigned int sA[16][68];  // padded rows: conflict-light
    int tid = threadIdx.x;
    int lane = tid & 63;
    int w = tid >> 6;  // wave 0..15 == tile slot
    int row0 = blockIdx.x * 16;
    int node = perm[row0 + w];  // wave-uniform broadcast load
    const unsigned int* xs32 = (const unsigned int*)xs;

    // ---- gather phase (R9-proven loop) ----
    if (node < N) {
        float dv = dinv[node];
        unsigned int sv = xs32[(size_t)node * 64 + lane];
        float a0 = bf2f((unsigned short)sv);
        float a1 = bf2f((unsigned short)(sv >> 16));
        int p = offs[node];
        if (p >= 0) {
            int pe = p + deg[node];
            for (; p + 16 <= pe; p += 16) {
                int u[16];
                unsigned int v[16];
#pragma unroll
                for (int j = 0; j < 16; ++j) u[j] = colidx[p + j];
#pragma unroll
                for (int j = 0; j < 16; ++j) v[j] = xs32[(size_t)u[j] * 64 + lane];
#pragma unroll
                for (int j = 0; j < 16; ++j) {
                    a0 += bf2f((unsigned short)v[j]);
                    a1 += bf2f((unsigned short)(v[j] >> 16));
                }
            }
            for (; p + 4 <= pe; p += 4) {
                int u[4];
                unsigned int v[4];
#pragma unroll
                for (int j = 0; j < 4; ++j) u[j] = colidx[p + j];
#pragma unroll
                for (int j = 0; j < 4; ++j) v[j] = xs32[(size_t)u[j] * 64 + lane];
#pragma unroll
                for (int j = 0; j < 4; ++j) {
                    a0 += bf2f((unsigned short)v[j]);
                    a1 += bf2f((unsigned short)(v[j] >> 16));
                }
            }
            for (; p < pe; ++p) {
                unsigned int v = xs32[(size_t)colidx[p] * 64 + lane];
                a0 += bf2f((unsigned short)v);
                a1 += bf2f((unsigned short)(v >> 16));
            }
        } else {
            // overflow-bucket node: gather via full edge scan (never on bench)
            for (int e = 0; e < E; ++e) {
                if (dst[e] == node) {
                    unsigned int v = xs32[(size_t)src[e] * 64 + lane];
                    a0 += bf2f((unsigned short)v);
                    a1 += bf2f((unsigned short)(v >> 16));
                }
            }
        }
        sA[w][lane] =
            (unsigned int)f2bf(dv * a0) | ((unsigned int)f2bf(dv * a1) << 16);
    } else {
        sA[w][lane] = 0u;
    }
    __syncthreads();

    // ---- GEMM phase: waves 0..7, cg = w; output rows via perm ----
    if (w < 8) {
        int m = lane & 15, quad = lane >> 4;
        short8 B[4];
#pragma unroll
        for (int ks = 0; ks < 4; ++ks)
            B[ks] = *(const short8*)&Wt[(size_t)(w * 16 + m) * D + ks * 32 + quad * 8];
        short8 A[4];
#pragma unroll
        for (int ks = 0; ks < 4; ++ks)
            A[ks] = *(const short8*)&sA[m][ks * 16 + quad * 4];
        floatx4 acc = {0.f, 0.f, 0.f, 0.f};
#pragma unroll
        for (int ks = 0; ks < 4; ++ks)
            acc = __builtin_amdgcn_mfma_f32_16x16x32_bf16(A[ks], B[ks], acc, 0, 0, 0);
        int col = w * 16 + m;
        float sc = scv[col], po = pov[col];
#pragma unroll
        for (int i = 0; i < 4; ++i) {
            int prow = perm[row0 + quad * 4 + i];
            if (prow < N) {
                float bn = acc[i] * sc + po;
                size_t idx = (size_t)prow * D + col;
                outp[idx] = fmaxf(bn, 0.f) + xg[idx];
            }
        }
    }
}

// ---------- fallback kernels (small-ws path) ----------
__global__ void wt_kernel(const float* __restrict__ W, const float* __restrict__ b,
                          const float* __restrict__ gamma, const float* __restrict__ beta,
                          const float* __restrict__ mean, const float* __restrict__ var,
                          unsigned short* __restrict__ Wt, float* __restrict__ scv,
                          float* __restrict__ pov) {
    int t = blockIdx.x * blockDim.x + threadIdx.x;
    int k = t >> 7, n = t & 127;
    Wt[(size_t)n * D + k] = f2bf(W[t]);
    if (t < D) {
        float sc = gamma[t] * rsqrtf(var[t] + BN_EPS);
        scv[t] = sc;
        pov[t] = (b[t] - mean[t]) * sc + beta[t];
    }
}

__global__ void deg_kernel(const int* __restrict__ dst, int* __restrict__ deg, int E) {
    int e = blockIdx.x * blockDim.x + threadIdx.x;
    if (e < E) atomicAdd(&deg[dst[e]], 1);
}

__global__ void dinv_kernel(const int* __restrict__ deg, float* __restrict__ dinv, int N) {
    int v = blockIdx.x * blockDim.x + threadIdx.x;
    if (v < N) dinv[v] = rsqrtf((float)(deg[v] + 1));
}

__global__ __launch_bounds__(256) void scan1_kernel(const int* __restrict__ deg,
                                                    int* __restrict__ bsum, int N) {
    __shared__ int s[256];
    int t = threadIdx.x;
    int v = blockIdx.x * 256 + t;
    s[t] = (v < N) ? deg[v] : 0;
    for (int st = 128; st > 0; st >>= 1) {
        __syncthreads();
        if (t < st) s[t] += s[t + st];
    }
    if (t == 0) bsum[blockIdx.x] = s[0];
}

__global__ __launch_bounds__(512) void scan2_kernel(int* __restrict__ bsum,
                                                    int* __restrict__ offs, int P, int N) {
    __shared__ int a[512];
    int t = threadIdx.x;
    int orig = (t < P) ? bsum[t] : 0;
    a[t] = orig;
    __syncthreads();
    for (int d = 1; d < 512; d <<= 1) {
        int tv = (t >= d) ? a[t - d] : 0;
        __syncthreads();
        a[t] += tv;
        __syncthreads();
    }
    if (t < P) bsum[t] = a[t] - orig;
    if (t == 0) offs[N] = a[511];
}

__global__ __launch_bounds__(256) void scan3_kernel(const int* __restrict__ deg,
                                                    const int* __restrict__ bsum,
                                                    int* __restrict__ offs,
                                                    int* __restrict__ cursor, int N) {
    __shared__ int a[256];
    int t = threadIdx.x;
    int v = blockIdx.x * 256 + t;
    int d = (v < N) ? deg[v] : 0;
    a[t] = d;
    __syncthreads();
    for (int st = 1; st < 256; st <<= 1) {
        int tv = (t >= st) ? a[t - st] : 0;
        __syncthreads();
        a[t] += tv;
        __syncthreads();
    }
    if (v < N) {
        int off = bsum[blockIdx.x] + a[t] - d;
        offs[v] = off;
        cursor[v] = off;
    }
}

__global__ void fill_kernel(const int* __restrict__ src, const int* __restrict__ dst,
                            int* __restrict__ cursor, int* __restrict__ colidx, int E) {
    int e = blockIdx.x * blockDim.x + threadIdx.x;
    if (e < E) {
        int d = dst[e];
        int pos = atomicAdd(&cursor[d], 1);
        colidx[pos] = src[e];
    }
}

// ---------- fallback aggregate (fp32, writes outp) ----------
__global__ __launch_bounds__(256) void agg_kernel(
    const float* __restrict__ x, const float* __restrict__ dinv,
    const int* __restrict__ offs, const int* __restrict__ deg,
    const int* __restrict__ colidx, float* __restrict__ outp, int N) {
    int wid = (blockIdx.x * blockDim.x + threadIdx.x) >> 6;
    if (wid >= N) return;
    int lane = threadIdx.x & 63;
    float dv = dinv[wid];
    int p = offs[wid];
    int pe = p + deg[wid];
    const float2* x2 = (const float2*)x;
    float2 s = x2[(size_t)wid * 64 + lane];
    float a0 = dv * s.x;
    float a1 = dv * s.y;
    for (; p < pe; ++p) {
        int u = colidx[p];
        float du = dinv[u];
        float2 vv = x2[(size_t)u * 64 + lane];
        a0 += du * vv.x;
        a1 += du * vv.y;
    }
    float2 r;
    r.x = dv * a0;
    r.y = dv * a1;
    ((float2*)outp)[(size_t)wid * 64 + lane] = r;
}

// ---------- fallback GEMM (reads fp32 outp in place) ----------
__global__ __launch_bounds__(256) void gemm_kernel(
    float* __restrict__ outp, const float* __restrict__ xg,
    const unsigned short* __restrict__ Wt, const float* __restrict__ scv,
    const float* __restrict__ pov, int nTiles) {
    __shared__ uint4 sW4[2048];  // 32KB: [row 0..127][c4 0..15] swizzled c4^=(row&7)
    int tid = threadIdx.x;
    const uint4* W4 = (const uint4*)Wt;
#pragma unroll
    for (int i = 0; i < 8; ++i) {
        int q = tid + i * 256;
        int row = q >> 4, c4 = q & 15;
        sW4[row * 16 + (c4 ^ (row & 7))] = W4[q];
    }
    __syncthreads();

    int wid = (blockIdx.x * blockDim.x + tid) >> 6;
    if (wid >= nTiles) return;
    int lane = tid & 63;
    int m = lane & 15, quad = lane >> 4;
    int row0 = wid * 16;

    short8 A[4];
    const float* arow = outp + (size_t)(row0 + m) * D;
#pragma unroll
    for (int ks = 0; ks < 4; ++ks) {
        float4 f0 = *(const float4*)(arow + ks * 32 + quad * 8);
        float4 f1 = *(const float4*)(arow + ks * 32 + quad * 8 + 4);
        short8 af;
        af[0] = (short)f2bf(f0.x); af[1] = (short)f2bf(f0.y);
        af[2] = (short)f2bf(f0.z); af[3] = (short)f2bf(f0.w);
        af[4] = (short)f2bf(f1.x); af[5] = (short)f2bf(f1.y);
        af[6] = (short)f2bf(f1.z); af[7] = (short)f2bf(f1.w);
        A[ks] = af;
    }

#pragma unroll
    for (int cg2 = 0; cg2 < 8; ++cg2) {
        int brow = cg2 * 16 + m;
        floatx4 acc = {0.f, 0.f, 0.f, 0.f};
#pragma unroll
        for (int ks = 0; ks < 4; ++ks) {
            short8 Bf = *(const short8*)&sW4[brow * 16 + ((ks * 4 + quad) ^ (m & 7))];
            acc = __builtin_amdgcn_mfma_f32_16x16x32_bf16(A[ks], Bf, acc, 0, 0, 0);
        }
        int col = cg2 * 16 + m;
        float sc = scv[col], po = pov[col];
#pragma unroll
        for (int i = 0; i < 4; ++i) {
            int row = row0 + quad * 4 + i;
            float bn = acc[i] * sc + po;
            size_t idx = (size_t)row * D + col;
            outp[idx] = fmaxf(bn, 0.f) + xg[idx];
        }
    }
}

extern "C" void kernel_launch(void* const* d_in, const int* in_sizes, int n_in,
                              void* d_out, int out_size, void* d_ws, size_t ws_size,
                              hipStream_t stream) {
    const float* x = (const float*)d_in[0];
    const int* edge = (const int*)d_in[1];
    const float* Wm = (const float*)d_in[2];
    const float* b = (const float*)d_in[3];
    const float* gamma = (const float*)d_in[4];
    const float* beta = (const float*)d_in[5];
    const float* mean = (const float*)d_in[6];
    const float* var = (const float*)d_in[7];
    float* out = (float*)d_out;

    int N = in_sizes[0] / D;
    int E = in_sizes[1] / 2;
    const int* src = edge;
    const int* dst = edge + E;
    int P = (N + 255) / 256;

    // ---- workspace layout ----
    char* w = (char*)d_ws;
    size_t cur = 0;
    auto take = [&](size_t bytes) -> void* {
        cur = (cur + 15) & ~(size_t)15;
        void* p = w + cur;
        cur += bytes;
        return p;
    };
    int* deg = (int*)take((size_t)N * 4);
    int* resCnt = (int*)take(NBUCK * 4);
    float* dinv = (float*)take((size_t)N * 4);
    int* offs = (int*)take((size_t)(N + 1) * 4);
    int* cursor = (int*)take((size_t)(N + 16) * 4);  // fast path: perm (N+16 padded)
    int* bsum = (int*)take((size_t)(P + 1) * 4);     // fast path: dcnt[0..127]+dcur[128..255]
    unsigned short* Wt = (unsigned short*)take((size_t)D * D * 2);
    float* scv = (float*)take(D * 4);
    float* pov = (float*)take(D * 4);
    int* colidx = (int*)take((size_t)E * 4);
    cur = (cur + 15) & ~(size_t)15;
    size_t fixedEnd = cur;

    size_t xsBytes = (size_t)N * D * 2;
    size_t pairsBytes = (size_t)NBUCK * CAP * 4;  // padded packed-u32 pairs
    size_t zoneBytes = (xsBytes > pairsBytes) ? xsBytes : pairsBytes;
    bool fast = (fixedEnd + xsBytes + zoneBytes <= ws_size) && (N < (1 << 24)) &&
                (P + 1 >= 256);

    unsigned short* xs = nullptr;
    unsigned int* pairs = nullptr;
    if (fast) {
        xs = (unsigned short*)(w + fixedEnd);
        pairs = (unsigned int*)(w + fixedEnd + xsBytes);  // dead after sortxs
    }

    if (fast) {
        int* perm = cursor;
        int* dcnt = bsum;
        int* dcur = bsum + 128;
        init_kernel<<<(D * D) / 256, 256, 0, stream>>>(Wm, b, gamma, beta, mean, var,
                                                       Wt, scv, pov, resCnt, dcnt, perm,
                                                       N);
        pB_kernel<<<128, 512, 0, stream>>>(src, dst, resCnt, pairs, E);
        sortxs_kernel<<<NBUCK, 512, 0, stream>>>(pairs, resCnt, src, dst, x, deg, offs,
                                                 colidx, dinv, xs, dcnt, N, E);
        dperm_kernel<<<256, 256, 0, stream>>>(deg, dcnt, dcur, perm, N);
        aggemm_kernel<<<(N + 15) / 16, 1024, 0, stream>>>(
            xs, dinv, offs, deg, colidx, src, dst, x, Wt, scv, pov, perm, out, N, E);
    } else {
        wt_kernel<<<(D * D) / 256, 256, 0, stream>>>(Wm, b, gamma, beta, mean, var, Wt,
                                                     scv, pov);
        hipMemsetAsync(deg, 0, sizeof(int) * N, stream);
        deg_kernel<<<(E + 255) / 256, 256, 0, stream>>>(dst, deg, E);
        dinv_kernel<<<(N + 255) / 256, 256, 0, stream>>>(deg, dinv, N);
        scan1_kernel<<<P, 256, 0, stream>>>(deg, bsum, N);
        scan2_kernel<<<1, 512, 0, stream>>>(bsum, offs, P, N);
        scan3_kernel<<<P, 256, 0, stream>>>(deg, bsum, offs, cursor, N);
        fill_kernel<<<(E + 255) / 256, 256, 0, stream>>>(src, dst, cursor, colidx, E);
        agg_kernel<<<(N * 64 + 255) / 256, 256, 0, stream>>>(x, dinv, offs, deg, colidx,
                                                             out, N);
        int nTiles = (N + 15) / 16;
        gemm_kernel<<<(nTiles * 64 + 255) / 256, 256, 0, stream>>>(out, x, Wt, scv, pov,
                                                                   nTiles);
    }
}

// Round 13
// 253.374 us; speedup vs baseline: 2.2368x; 2.2368x over previous
//
#include <hip/hip_runtime.h>

#define D 128
#define BN_EPS 1e-5f
#define NBUCK 512     // coarse buckets, dst>>8 (391 used at N=100K), 256 nodes/bucket
#define BSHIFT 8
#define BNODES 256    // nodes per bucket
#define CAP 4608      // padded slots/bucket; mean fill 4096 (+8 sigma)
#define PBCHUNK 6272  // LDS-staged edges per pB block

using short8 = __attribute__((ext_vector_type(8))) short;
using floatx4 = __attribute__((ext_vector_type(4))) float;

__device__ inline unsigned short f2bf(float f) {
    unsigned u = __float_as_uint(f);
    u += 0x7fff + ((u >> 16) & 1);  // RNE
    return (unsigned short)(u >> 16);
}
__device__ inline float bf2f(unsigned short s) {
    return __uint_as_float(((unsigned)s) << 16);
}

// ---------- init: zero resCnt + Wt transpose + BN affine (tiny, 1 node) ----
__global__ __launch_bounds__(256) void init_kernel(
    const float* __restrict__ W, const float* __restrict__ b,
    const float* __restrict__ gamma, const float* __restrict__ beta,
    const float* __restrict__ mean, const float* __restrict__ var,
    unsigned short* __restrict__ Wt, float* __restrict__ scv,
    float* __restrict__ pov, int* __restrict__ resCnt) {
    int t = blockIdx.x * 256 + threadIdx.x;  // 0..16383 == D*D
    Wt[(size_t)(t & 127) * D + (t >> 7)] = f2bf(W[t]);
    if (t < NBUCK) resCnt[t] = 0;
    if (t < D) {
        float sc = gamma[t] * rsqrtf(var[t] + BN_EPS);
        scv[t] = sc;
        pov[t] = (b[t] - mean[t]) * sc + beta[t];
    }
}

// ---------- pB: partition into CAPACITY-PADDED buckets, LDS-staged ----------
// R11 analysis: the R9 direct scatter touched each pairs line ~25x while its
// run filled, thrashing the 4MB XCD L2 (9.4MB region / 16 blocks per XCD) ->
// ~25 RMW round-trips per line. Fix: two-pass within the block. Scatter the
// chunk into LDS bucket-ordered (ord+bkt, ~43KB), then a LINEAR out-copy in
// which consecutive threads write consecutive addresses within each run ->
// every pairs line is written in one temporal burst (1 fetch/evict).
// pairs entry = (dst&255)<<24 | src (valid: N < 2^24). Run base =
// bucket*CAP + atomicAdd(resCnt) (one atomic per bucket per block).
// Overflow (resCnt>CAP, ~impossible) drops here, recovered in sortxs/agg.
__global__ __launch_bounds__(512) void pB_kernel(const int* __restrict__ src,
                                                 const int* __restrict__ dst,
                                                 int* __restrict__ resCnt,
                                                 unsigned int* __restrict__ pairs,
                                                 int E) {
    __shared__ int lh[NBUCK];        // hist, then lcur
    __shared__ int excl[NBUCK];      // scan scratch, then exclusive offsets
    __shared__ int resBase[NBUCK];   // global run base per bucket
    __shared__ unsigned int ord[PBCHUNK];
    __shared__ unsigned short bkt[PBCHUNK];
    int tid = threadIdx.x;
    lh[tid] = 0;
    __syncthreads();
    int chunk = (E + gridDim.x - 1) / gridDim.x;  // <= PBCHUNK by grid choice
    int base = blockIdx.x * chunk;
    int lim = min(chunk, E - base);
    if (lim <= 0) return;
    for (int i = tid; i < lim; i += 512) atomicAdd(&lh[dst[base + i] >> BSHIFT], 1);
    __syncthreads();
    int c = lh[tid];
    excl[tid] = c;
    __syncthreads();
    for (int d = 1; d < NBUCK; d <<= 1) {
        int v = (tid >= d) ? excl[tid - d] : 0;
        __syncthreads();
        excl[tid] += v;
        __syncthreads();
    }
    int myExcl = excl[tid] - c;  // exclusive local offset for bucket tid
    resBase[tid] = tid * CAP + (c ? atomicAdd(&resCnt[tid], c) : 0);
    __syncthreads();
    excl[tid] = myExcl;
    lh[tid] = myExcl;  // lcur
    __syncthreads();
    // pass 2: scatter chunk into LDS, bucket-ordered
    for (int i = tid; i < lim; i += 512) {
        int s = src[base + i], d2 = dst[base + i];
        int b2 = d2 >> BSHIFT;
        int pos = atomicAdd(&lh[b2], 1);
        ord[pos] = (((unsigned)d2 & 255u) << 24) | (unsigned)s;
        bkt[pos] = (unsigned short)b2;
    }
    __syncthreads();
    // out-copy: linear; consecutive i in a bucket -> consecutive global dest
    for (int i = tid; i < lim; i += 512) {
        int b2 = bkt[i];
        int dest = resBase[b2] + (i - excl[b2]);
        if (dest < (b2 + 1) * CAP) pairs[dest] = ord[i];
    }
}

// ---------- sortxs: per-bucket counting sort + premult xs build ----------
// Compact colidx bases come from a 512-wide LDS scan of resCnt (2KB, L2-hot)
// so colidx stays E-sized and the ws footprint == proven R4 layout.
// Overflow bucket (cnt>CAP): offs=-1 marker, deg/dinv from full edge scan.
__global__ __launch_bounds__(512) void sortxs_kernel(
    const unsigned int* __restrict__ pairs, const int* __restrict__ resCnt,
    const int* __restrict__ src, const int* __restrict__ dst,
    const float* __restrict__ x, int* __restrict__ deg, int* __restrict__ offs,
    int* __restrict__ colidx, float* __restrict__ dinv,
    unsigned short* __restrict__ xs, int N, int E) {
    __shared__ int sb[NBUCK];
    __shared__ int lh[BNODES];
    __shared__ int lcur[BNODES];
    __shared__ float sdv[BNODES];
    int tid = threadIdx.x;
    int b = blockIdx.x;
    sb[tid] = resCnt[tid];
    __syncthreads();
    for (int d = 1; d < NBUCK; d <<= 1) {
        int v = (tid >= d) ? sb[tid - d] : 0;
        __syncthreads();
        sb[tid] += v;
        __syncthreads();
    }
    int cnt = resCnt[b];
    int cbase = sb[b] - cnt;       // compact colidx base
    int pbase = b * CAP;           // padded pairs base
    if (tid < BNODES) lh[tid] = 0;
    __syncthreads();

    if (cnt <= CAP) {
        // ---- normal path ----
        for (int i = tid; i < cnt; i += 512)
            atomicAdd(&lh[pairs[pbase + i] >> 24], 1);
        __syncthreads();
        int orig = (tid < BNODES) ? lh[tid] : 0;
        for (int d = 1; d < BNODES; d <<= 1) {
            int v = (tid < BNODES && tid >= d) ? lh[tid - d] : 0;
            __syncthreads();
            if (tid < BNODES) lh[tid] += v;
            __syncthreads();
        }
        if (tid < BNODES) {
            int exc = lh[tid] - orig;
            int node = b * BNODES + tid;
            float dvv = rsqrtf((float)(orig + 1));
            sdv[tid] = dvv;
            if (node < N) {
                deg[node] = orig;
                offs[node] = cbase + exc;
                dinv[node] = dvv;
            }
            lcur[tid] = exc;
        }
        __syncthreads();
        for (int i = tid; i < cnt; i += 512) {
            unsigned int p = pairs[pbase + i];
            int pos = atomicAdd(&lcur[p >> 24], 1);
            colidx[cbase + pos] = (int)(p & 0x00FFFFFFu);
        }
    } else {
        // ---- overflow recovery: exact deg from full edge scan; no colidx ----
        for (int i = tid; i < E; i += 512) {
            int d2 = dst[i];
            if ((d2 >> BSHIFT) == b) atomicAdd(&lh[d2 & 255], 1);
        }
        __syncthreads();
        if (tid < BNODES) {
            int orig = lh[tid];
            int node = b * BNODES + tid;
            float dvv = rsqrtf((float)(orig + 1));
            sdv[tid] = dvv;
            if (node < N) {
                deg[node] = orig;
                offs[node] = -1;  // agg falls back to full scan for this node
                dinv[node] = dvv;
            }
        }
        __syncthreads();
    }

    // ---- xs build for this bucket's nodes: xs = bf16(dinv[n] * x[n]) ----
    int nb = min(BNODES, N - b * BNODES);
    if (nb > 0) {
        const float4* x4 = (const float4*)x;
        ushort4* xs4 = (ushort4*)xs;
        int tot = nb * 32;  // 32 float4 chunks per node
        for (int c2 = tid; c2 < tot; c2 += 512) {
            int nl = c2 >> 5, q = c2 & 31;
            int node = b * BNODES + nl;
            float dvv = sdv[nl];
            float4 f = x4[(size_t)node * 32 + q];
            ushort4 o;
            o.x = f2bf(dvv * f.x); o.y = f2bf(dvv * f.y);
            o.z = f2bf(dvv * f.z); o.w = f2bf(dvv * f.w);
            xs4[(size_t)node * 32 + q] = o;
        }
    }
}

// ---------- fallback kernels (small-ws path) ----------
__global__ void wt_kernel(const float* __restrict__ W, const float* __restrict__ b,
                          const float* __restrict__ gamma, const float* __restrict__ beta,
                          const float* __restrict__ mean, const float* __restrict__ var,
                          unsigned short* __restrict__ Wt, float* __restrict__ scv,
                          float* __restrict__ pov) {
    int t = blockIdx.x * blockDim.x + threadIdx.x;
    int k = t >> 7, n = t & 127;
    Wt[(size_t)n * D + k] = f2bf(W[t]);
    if (t < D) {
        float sc = gamma[t] * rsqrtf(var[t] + BN_EPS);
        scv[t] = sc;
        pov[t] = (b[t] - mean[t]) * sc + beta[t];
    }
}

__global__ void deg_kernel(const int* __restrict__ dst, int* __restrict__ deg, int E) {
    int e = blockIdx.x * blockDim.x + threadIdx.x;
    if (e < E) atomicAdd(&deg[dst[e]], 1);
}

__global__ void dinv_kernel(const int* __restrict__ deg, float* __restrict__ dinv, int N) {
    int v = blockIdx.x * blockDim.x + threadIdx.x;
    if (v < N) dinv[v] = rsqrtf((float)(deg[v] + 1));
}

__global__ __launch_bounds__(256) void scan1_kernel(const int* __restrict__ deg,
                                                    int* __restrict__ bsum, int N) {
    __shared__ int s[256];
    int t = threadIdx.x;
    int v = blockIdx.x * 256 + t;
    s[t] = (v < N) ? deg[v] : 0;
    for (int st = 128; st > 0; st >>= 1) {
        __syncthreads();
        if (t < st) s[t] += s[t + st];
    }
    if (t == 0) bsum[blockIdx.x] = s[0];
}

__global__ __launch_bounds__(512) void scan2_kernel(int* __restrict__ bsum,
                                                    int* __restrict__ offs, int P, int N) {
    __shared__ int a[512];
    int t = threadIdx.x;
    int orig = (t < P) ? bsum[t] : 0;
    a[t] = orig;
    __syncthreads();
    for (int d = 1; d < 512; d <<= 1) {
        int tv = (t >= d) ? a[t - d] : 0;
        __syncthreads();
        a[t] += tv;
        __syncthreads();
    }
    if (t < P) bsum[t] = a[t] - orig;
    if (t == 0) offs[N] = a[511];
}

__global__ __launch_bounds__(256) void scan3_kernel(const int* __restrict__ deg,
                                                    const int* __restrict__ bsum,
                                                    int* __restrict__ offs,
                                                    int* __restrict__ cursor, int N) {
    __shared__ int a[256];
    int t = threadIdx.x;
    int v = blockIdx.x * 256 + t;
    int d = (v < N) ? deg[v] : 0;
    a[t] = d;
    __syncthreads();
    for (int st = 1; st < 256; st <<= 1) {
        int tv = (t >= st) ? a[t - st] : 0;
        __syncthreads();
        a[t] += tv;
        __syncthreads();
    }
    if (v < N) {
        int off = bsum[blockIdx.x] + a[t] - d;
        offs[v] = off;
        cursor[v] = off;
    }
}

__global__ void fill_kernel(const int* __restrict__ src, const int* __restrict__ dst,
                            int* __restrict__ cursor, int* __restrict__ colidx, int E) {
    int e = blockIdx.x * blockDim.x + threadIdx.x;
    if (e < E) {
        int d = dst[e];
        int pos = atomicAdd(&cursor[d], 1);
        colidx[pos] = src[e];
    }
}

// ---------- gather-aggregate: one wave/node, lane = 2 packed cols ----------
// R4/R9-proven body; pe = offs + deg (supports overflow marker offs<0).
__global__ __launch_bounds__(256) void agg_kernel(
    const float* __restrict__ x, const unsigned short* __restrict__ xs,
    const float* __restrict__ dinv, const int* __restrict__ offs,
    const int* __restrict__ deg, const int* __restrict__ colidx,
    const int* __restrict__ src, const int* __restrict__ dst,
    float* __restrict__ outp, unsigned int* __restrict__ aggb, int N, int E) {
    int wid = (blockIdx.x * blockDim.x + threadIdx.x) >> 6;
    if (wid >= N) return;
    int lane = threadIdx.x & 63;
    float dv = dinv[wid];
    float a0, a1;
    int p = offs[wid];
    if (xs) {
        const unsigned int* xs32 = (const unsigned int*)xs;
        unsigned int sv = xs32[(size_t)wid * 64 + lane];
        a0 = bf2f((unsigned short)sv);
        a1 = bf2f((unsigned short)(sv >> 16));
        if (p >= 0) {
            int pe = p + deg[wid];
            for (; p + 16 <= pe; p += 16) {
                int u[16];
                unsigned int v[16];
#pragma unroll
                for (int j = 0; j < 16; ++j) u[j] = colidx[p + j];
#pragma unroll
                for (int j = 0; j < 16; ++j) v[j] = xs32[(size_t)u[j] * 64 + lane];
#pragma unroll
                for (int j = 0; j < 16; ++j) {
                    a0 += bf2f((unsigned short)v[j]);
                    a1 += bf2f((unsigned short)(v[j] >> 16));
                }
            }
            for (; p + 4 <= pe; p += 4) {
                int u[4];
                unsigned int v[4];
#pragma unroll
                for (int j = 0; j < 4; ++j) u[j] = colidx[p + j];
#pragma unroll
                for (int j = 0; j < 4; ++j) v[j] = xs32[(size_t)u[j] * 64 + lane];
#pragma unroll
                for (int j = 0; j < 4; ++j) {
                    a0 += bf2f((unsigned short)v[j]);
                    a1 += bf2f((unsigned short)(v[j] >> 16));
                }
            }
            for (; p < pe; ++p) {
                unsigned int v = xs32[(size_t)colidx[p] * 64 + lane];
                a0 += bf2f((unsigned short)v);
                a1 += bf2f((unsigned short)(v >> 16));
            }
        } else {
            // overflow-bucket node: gather via full edge scan (never on bench)
            for (int e = 0; e < E; ++e) {
                if (dst[e] == wid) {
                    unsigned int v = xs32[(size_t)src[e] * 64 + lane];
                    a0 += bf2f((unsigned short)v);
                    a1 += bf2f((unsigned short)(v >> 16));
                }
            }
        }
        aggb[(size_t)wid * 64 + lane] =
            (unsigned int)f2bf(dv * a0) | ((unsigned int)f2bf(dv * a1) << 16);
    } else {
        const float2* x2 = (const float2*)x;
        float2 s = x2[(size_t)wid * 64 + lane];
        a0 = dv * s.x;
        a1 = dv * s.y;
        int pe = p + deg[wid];
        for (; p < pe; ++p) {
            int u = colidx[p];
            float du = dinv[u];
            float2 vv = x2[(size_t)u * 64 + lane];
            a0 += du * vv.x;
            a1 += du * vv.y;
        }
        float2 r;
        r.x = dv * a0;
        r.y = dv * a1;
        ((float2*)outp)[(size_t)wid * 64 + lane] = r;
    }
}

// ---------- MFMA GEMM: out = relu(BN(agg @ W + b)) + x (R4 body, no nt) ----
__global__ __launch_bounds__(256) void gemm_kernel(
    float* __restrict__ outp, const float* __restrict__ xg,
    const unsigned short* __restrict__ Wt, const unsigned short* __restrict__ aggb,
    const float* __restrict__ scv, const float* __restrict__ pov, int nTiles) {
    __shared__ uint4 sW4[2048];  // 32KB: [row 0..127][c4 0..15] swizzled c4^=(row&7)
    int tid = threadIdx.x;
    const uint4* W4 = (const uint4*)Wt;
#pragma unroll
    for (int i = 0; i < 8; ++i) {
        int q = tid + i * 256;  // uint4 index 0..2047
        int row = q >> 4, c4 = q & 15;
        sW4[row * 16 + (c4 ^ (row & 7))] = W4[q];
    }
    __syncthreads();

    int wid = (blockIdx.x * blockDim.x + tid) >> 6;
    if (wid >= nTiles) return;
    int lane = tid & 63;
    int m = lane & 15, quad = lane >> 4;
    int row0 = wid * 16;

    short8 A[4];
    if (aggb) {
        const unsigned short* arow = aggb + (size_t)(row0 + m) * D;
#pragma unroll
        for (int ks = 0; ks < 4; ++ks)
            A[ks] = *(const short8*)&arow[ks * 32 + quad * 8];
    } else {
        const float* arow = outp + (size_t)(row0 + m) * D;
#pragma unroll
        for (int ks = 0; ks < 4; ++ks) {
            float4 f0 = *(const float4*)(arow + ks * 32 + quad * 8);
            float4 f1 = *(const float4*)(arow + ks * 32 + quad * 8 + 4);
            short8 af;
            af[0] = (short)f2bf(f0.x); af[1] = (short)f2bf(f0.y);
            af[2] = (short)f2bf(f0.z); af[3] = (short)f2bf(f0.w);
            af[4] = (short)f2bf(f1.x); af[5] = (short)f2bf(f1.y);
            af[6] = (short)f2bf(f1.z); af[7] = (short)f2bf(f1.w);
            A[ks] = af;
        }
    }

#pragma unroll
    for (int cg2 = 0; cg2 < 8; ++cg2) {
        int brow = cg2 * 16 + m;
        floatx4 acc = {0.f, 0.f, 0.f, 0.f};
#pragma unroll
        for (int ks = 0; ks < 4; ++ks) {
            short8 Bf = *(const short8*)&sW4[brow * 16 + ((ks * 4 + quad) ^ (m & 7))];
            acc = __builtin_amdgcn_mfma_f32_16x16x32_bf16(A[ks], Bf, acc, 0, 0, 0);
        }
        int col = cg2 * 16 + m;
        float sc = scv[col], po = pov[col];
#pragma unroll
        for (int i = 0; i < 4; ++i) {
            int row = row0 + quad * 4 + i;
            float bn = acc[i] * sc + po;
            size_t idx = (size_t)row * D + col;
            outp[idx] = fmaxf(bn, 0.f) + xg[idx];
        }
    }
}

extern "C" void kernel_launch(void* const* d_in, const int* in_sizes, int n_in,
                              void* d_out, int out_size, void* d_ws, size_t ws_size,
                              hipStream_t stream) {
    const float* x = (const float*)d_in[0];
    const int* edge = (const int*)d_in[1];
    const float* Wm = (const float*)d_in[2];
    const float* b = (const float*)d_in[3];
    const float* gamma = (const float*)d_in[4];
    const float* beta = (const float*)d_in[5];
    const float* mean = (const float*)d_in[6];
    const float* var = (const float*)d_in[7];
    float* out = (float*)d_out;

    int N = in_sizes[0] / D;
    int E = in_sizes[1] / 2;
    const int* src = edge;
    const int* dst = edge + E;
    int P = (N + 255) / 256;

    // ---- workspace layout (fixed area identical to proven R4 footprint) ----
    char* w = (char*)d_ws;
    size_t cur = 0;
    auto take = [&](size_t bytes) -> void* {
        cur = (cur + 15) & ~(size_t)15;
        void* p = w + cur;
        cur += bytes;
        return p;
    };
    int* deg = (int*)take((size_t)N * 4);
    int* resCnt = (int*)take(NBUCK * 4);
    float* dinv = (float*)take((size_t)N * 4);
    int* offs = (int*)take((size_t)(N + 1) * 4);
    int* cursor = (int*)take((size_t)N * 4);
    int* bsum = (int*)take((size_t)(P + 1) * 4);
    unsigned short* Wt = (unsigned short*)take((size_t)D * D * 2);
    float* scv = (float*)take(D * 4);
    float* pov = (float*)take(D * 4);
    int* colidx = (int*)take((size_t)E * 4);
    cur = (cur + 15) & ~(size_t)15;
    size_t fixedEnd = cur;

    size_t xsBytes = (size_t)N * D * 2;
    size_t pairsBytes = (size_t)NBUCK * CAP * 4;  // padded packed-u32 pairs
    size_t zoneBytes = (xsBytes > pairsBytes) ? xsBytes : pairsBytes;
    bool fast = (fixedEnd + xsBytes + zoneBytes <= ws_size) && (N < (1 << 24));

    unsigned short* xs = nullptr;
    unsigned int* pairs = nullptr;
    unsigned int* aggb = nullptr;
    if (fast) {
        xs = (unsigned short*)(w + fixedEnd);
        pairs = (unsigned int*)(w + fixedEnd + xsBytes);  // dead after sortxs
        aggb = (unsigned int*)(w + fixedEnd + xsBytes);   // aliases pairs
    }

    if (fast) {
        int pgrid = (E + PBCHUNK - 1) / PBCHUNK;  // chunk <= PBCHUNK by construction
        init_kernel<<<(D * D) / 256, 256, 0, stream>>>(Wm, b, gamma, beta, mean, var,
                                                       Wt, scv, pov, resCnt);
        pB_kernel<<<pgrid, 512, 0, stream>>>(src, dst, resCnt, pairs, E);
        sortxs_kernel<<<NBUCK, 512, 0, stream>>>(pairs, resCnt, src, dst, x, deg, offs,
                                                 colidx, dinv, xs, N, E);
        agg_kernel<<<(N * 64 + 255) / 256, 256, 0, stream>>>(
            x, xs, dinv, offs, deg, colidx, src, dst, out, aggb, N, E);
        int nTiles = (N + 15) / 16;
        gemm_kernel<<<(nTiles * 64 + 255) / 256, 256, 0, stream>>>(
            out, x, Wt, (const unsigned short*)aggb, scv, pov, nTiles);
    } else {
        wt_kernel<<<(D * D) / 256, 256, 0, stream>>>(Wm, b, gamma, beta, mean, var, Wt,
                                                     scv, pov);
        hipMemsetAsync(deg, 0, sizeof(int) * N, stream);
        deg_kernel<<<(E + 255) / 256, 256, 0, stream>>>(dst, deg, E);
        dinv_kernel<<<(N + 255) / 256, 256, 0, stream>>>(deg, dinv, N);
        scan1_kernel<<<P, 256, 0, stream>>>(deg, bsum, N);
        scan2_kernel<<<1, 512, 0, stream>>>(bsum, offs, P, N);
        scan3_kernel<<<P, 256, 0, stream>>>(deg, bsum, offs, cursor, N);
        fill_kernel<<<(E + 255) / 256, 256, 0, stream>>>(src, dst, cursor, colidx, E);
        agg_kernel<<<(N * 64 + 255) / 256, 256, 0, stream>>>(
            x, nullptr, dinv, offs, deg, colidx, src, dst, out, nullptr, N, E);
        int nTiles = (N + 15) / 16;
        gemm_kernel<<<(nTiles * 64 + 255) / 256, 256, 0, stream>>>(out, x, Wt, nullptr,
                                                                   scv, pov, nTiles);
    }
}